// Round 6
// baseline (748.512 us; speedup 1.0000x reference)
//
#include <hip/hip_runtime.h>
#include <stdint.h>

// L=S=1024, N=16, E=1024, single head. f32 in/out, bf16 MFMA internally.
//
// R10: conversion folded into GEMM staging. Two staging paths in gemm_bt2:
//   INF32=false (scores, PV): R8's proven g2l16 ring-4 bf16 path, unchanged.
//   INF32=true (Qproj, Kproj, Vt): reads f32 A and B directly. T14 split:
//     global f32 -> regs (tile kt+2 issued during tile kt), convert (manual
//     RNE) -> ds_write_b128 (tile kt+1), double-buffered LDS (2 x 32KB),
//     one lgkmcnt(0)+barrier per tile. Same swizzle maps as g2l path.
// Removes cvt_all (62us) + cvt_one (~30us) dispatches and 140MB of HBM
// round-trip. 6 dispatches total:
//   Qproj(query,wq)->OC ; Kproj(key,wk)->OD ; scores(OC,OD)->WSB ;
//   softmax WSB ; Vt(wv,valp)->WSA ; PV(WSB,WSA)->d_out.

typedef __attribute__((ext_vector_type(8))) short bf16x8;   // 8 bf16 = 4 VGPRs
typedef __attribute__((ext_vector_type(4))) float f32x4;    // MFMA 16x16 accum

__device__ __forceinline__ float bf2f(unsigned short u) {
    union { unsigned int i; float f; } w; w.i = ((unsigned int)u) << 16; return w.f;
}
__device__ __forceinline__ unsigned short f2bf(float f) {
    union { float f; unsigned int i; } w; w.f = f;
    unsigned int r = (w.i + 0x7FFFu + ((w.i >> 16) & 1u)) >> 16;  // RNE
    return (unsigned short)r;
}

// async global->LDS, 16B/lane; LDS dest is wave-uniform base + lane*16B
__device__ __forceinline__ void g2l16(const unsigned short* g, unsigned short* l) {
    __builtin_amdgcn_global_load_lds(
        (const __attribute__((address_space(1))) unsigned int*)g,
        (__attribute__((address_space(3))) unsigned int*)l, 16, 0, 0);
}

#define BM 256
#define BN 256
#define BK 32

// convert 8 f32 (two float4) -> bf16x8 and store to LDS
#define CVT8(dst8, r0, r1)                                                     \
    {                                                                          \
        bf16x8 _v;                                                             \
        _v[0] = (short)f2bf((r0).x); _v[1] = (short)f2bf((r0).y);              \
        _v[2] = (short)f2bf((r0).z); _v[3] = (short)f2bf((r0).w);              \
        _v[4] = (short)f2bf((r1).x); _v[5] = (short)f2bf((r1).y);              \
        _v[6] = (short)f2bf((r1).z); _v[7] = (short)f2bf((r1).w);              \
        *(bf16x8*)(dst8) = _v;                                                 \
    }

// C[m][col] = (sum_k A[m,k]*B[col,k] + bias) * scale.
// BIAS_MODE: 0 none, 1 per-col, 2 per-row. K multiple of 32, K/32 >= 4.
// INF32: A,B are f32 (converted in staging). lda/ldb/aBatch/bBatch are in
// ELEMENTS of the input type; ldc/cBatch in elements of OutT.
// Grid MUST be exactly 256 blocks (8 XCDs x 32 chunk).
template <int BIAS_MODE, typename OutT, bool INF32>
__global__ __launch_bounds__(1024, 4) void gemm_bt2(
    const void* __restrict__ Av,
    const void* __restrict__ Bv,
    OutT* __restrict__ C,
    const float* __restrict__ bias,
    float scale, int K,
    long lda, long ldb, long ldc,
    long aBatch, long bBatch, long cBatch,
    int gridM, int gridN)
{
    // bf16 path: ring of 4 x (A 8K + B 8K shorts). f32 path: 2 bufs.
    // Epilogue reuses all 128KB.
    __shared__ __align__(16) unsigned short lds[65536];   // 128 KiB

    const int tid  = threadIdx.x;
    const int wave = tid >> 6;      // 0..15
    const int lane = tid & 63;
    const int lr   = lane & 15;
    const int q4   = lane >> 4;
    const int wm   = wave >> 2;     // 0..3  (M quarter)
    const int wn   = wave & 3;      // 0..3  (N quarter)

    // chunked XCD swizzle: physical p -> logical l; XCD (p%8) owns 32
    // consecutive logical blocks; bcol-fast decode keeps panel sharers
    // on one XCD's L2.
    const int p    = blockIdx.x;
    const int l    = ((p & 7) << 5) + (p >> 3);
    const int bcol = l % gridN;
    const int t2   = l / gridN;
    const int brow = t2 % gridM;
    const int bz   = t2 / gridM;

    const long m0 = (long)brow * BM;
    const long n0 = (long)bcol * BN;

    // staging map: physical 16B chunk pc = tid holds logical chunk
    // lc = pc ^ ((pc>>3)&7) (involution). row = lc>>2 (0..255), k-chunk = lc&3.
    const int tswz  = tid ^ ((tid >> 3) & 7);
    const int srow  = tswz >> 2;          // 0..255
    const int skoff = (tswz & 3) * 8;     // element offset in k

    // swizzled fragment read offset (lane constant, in ushorts)
    const int myoff = (((lr << 2) | q4) ^ ((lr >> 1) & 7)) << 3;

    f32x4 acc[4][4];
    const f32x4 zero = {0.f, 0.f, 0.f, 0.f};
#pragma unroll
    for (int m = 0; m < 4; m++)
#pragma unroll
        for (int n = 0; n < 4; n++) acc[m][n] = zero;

    const int nkt = K / BK;   // 32 here

    if constexpr (!INF32) {
        // ================= bf16 inputs: g2l16 ring-4 path (R8) =================
        const unsigned short* A = (const unsigned short*)Av + (long)bz * aBatch;
        const unsigned short* B = (const unsigned short*)Bv + (long)bz * bBatch;
        const unsigned short* aS = A + (m0 + srow) * lda + skoff;
        const unsigned short* bS = B + (n0 + srow) * ldb + skoff;
        const int ldsW = wave * 512;          // wave's 1KB slice per stage inst

        // prologue: stage tiles 0..2 into bufs 0..2
#pragma unroll
        for (int t = 0; t < 3; t++) {
            const long kb = (long)t * BK;
            unsigned short* base = &lds[t * 16384];
            g2l16(aS + kb, base + ldsW);
            g2l16(bS + kb, base + 8192 + ldsW);
        }
        asm volatile("s_waitcnt vmcnt(4)" ::: "memory");   // tile 0 landed
        __builtin_amdgcn_sched_barrier(0);
        __builtin_amdgcn_s_barrier();

        for (int kt = 0; kt < nkt; kt++) {
            const int buf  = kt & 3;
            const int sbuf = (kt + 3) & 3;                       // read-retired at kt-1
            const int st   = (kt + 3 < nkt) ? kt + 3 : nkt - 1;  // clamp: dummy re-stage
            const long kb  = (long)st * BK;
            const unsigned short* At = &lds[buf * 16384];
            const unsigned short* Bt = At + 8192;
            unsigned short* sb = &lds[sbuf * 16384];

            g2l16(aS + kb, sb + ldsW);
            g2l16(bS + kb, sb + 8192 + ldsW);

            bf16x8 af[4], bfr[4];
#pragma unroll
            for (int m = 0; m < 4; m++)
                af[m] = *(const bf16x8*)&At[(wm * 64 + m * 16) * 32 + myoff];
#pragma unroll
            for (int n = 0; n < 4; n++)
                bfr[n] = *(const bf16x8*)&Bt[(wn * 64 + n * 16) * 32 + myoff];

            __builtin_amdgcn_s_setprio(1);
#pragma unroll
            for (int m = 0; m < 4; m++)
#pragma unroll
                for (int n = 0; n < 4; n++)
                    acc[m][n] = __builtin_amdgcn_mfma_f32_16x16x32_bf16(
                        af[m], bfr[n], acc[m][n], 0, 0, 0);
            __builtin_amdgcn_s_setprio(0);

            // counted: tiles kt+2,kt+3 (4 loads) stay in flight.
            asm volatile("s_waitcnt vmcnt(4)" ::: "memory");
            __builtin_amdgcn_sched_barrier(0);
            __builtin_amdgcn_s_barrier();
        }
        asm volatile("s_waitcnt vmcnt(0)" ::: "memory");   // drain dummy re-stages
    } else {
        // ============ f32 inputs: reg-stage + convert, double buffer ============
        const float* A = (const float*)Av + (long)bz * aBatch;
        const float* B = (const float*)Bv + (long)bz * bBatch;
        const float* aF = A + (m0 + srow) * lda + skoff;
        const float* bF = B + (n0 + srow) * ldb + skoff;

        float4 sa0, sa1, sb0, sb1;
        // prologue: stage tile 0 into buf0, issue loads for tile 1
        sa0 = ((const float4*)aF)[0]; sa1 = ((const float4*)aF)[1];
        sb0 = ((const float4*)bF)[0]; sb1 = ((const float4*)bF)[1];
        {
            unsigned short* w = &lds[tid * 8];
            CVT8(w, sa0, sa1);
            CVT8(w + 8192, sb0, sb1);
        }
        if (nkt > 1) {
            sa0 = ((const float4*)(aF + BK))[0]; sa1 = ((const float4*)(aF + BK))[1];
            sb0 = ((const float4*)(bF + BK))[0]; sb1 = ((const float4*)(bF + BK))[1];
        }
        asm volatile("s_waitcnt lgkmcnt(0)" ::: "memory");
        __builtin_amdgcn_sched_barrier(0);
        __builtin_amdgcn_s_barrier();

        for (int kt = 0; kt < nkt; kt++) {
            const unsigned short* At = &lds[(kt & 1) * 16384];
            const unsigned short* Bt = At + 8192;

            bf16x8 af[4], bfr[4];
#pragma unroll
            for (int m = 0; m < 4; m++)
                af[m] = *(const bf16x8*)&At[(wm * 64 + m * 16) * 32 + myoff];
#pragma unroll
            for (int n = 0; n < 4; n++)
                bfr[n] = *(const bf16x8*)&Bt[(wn * 64 + n * 16) * 32 + myoff];

            // publish tile kt+1 (regs loaded during kt-1 / prologue)
            if (kt + 1 < nkt) {
                unsigned short* w = &lds[((kt + 1) & 1) * 16384 + tid * 8];
                CVT8(w, sa0, sa1);
                CVT8(w + 8192, sb0, sb1);
            }
            // issue loads for tile kt+2 (a full tile of latency to land)
            if (kt + 2 < nkt) {
                const float* pa = aF + (long)(kt + 2) * BK;
                const float* pb = bF + (long)(kt + 2) * BK;
                sa0 = ((const float4*)pa)[0]; sa1 = ((const float4*)pa)[1];
                sb0 = ((const float4*)pb)[0]; sb1 = ((const float4*)pb)[1];
            }

            __builtin_amdgcn_s_setprio(1);
#pragma unroll
            for (int m = 0; m < 4; m++)
#pragma unroll
                for (int n = 0; n < 4; n++)
                    acc[m][n] = __builtin_amdgcn_mfma_f32_16x16x32_bf16(
                        af[m], bfr[n], acc[m][n], 0, 0, 0);
            __builtin_amdgcn_s_setprio(0);

            // publish ds_writes + frag reads retired; loads stay in flight.
            asm volatile("s_waitcnt lgkmcnt(0)" ::: "memory");
            __builtin_amdgcn_sched_barrier(0);
            __builtin_amdgcn_s_barrier();
        }
    }

    C += (long)bz * cBatch;

    // ==================== LDS-staged coalesced epilogue ====================
    __syncthreads();

    if constexpr (sizeof(OutT) == 2) {
        // bf16: whole 256x256 tile fits (128KB). q4-XOR swizzle keeps the
        // b16 scatter writes conflict-free (verified: 0 conflicts).
#pragma unroll
        for (int m = 0; m < 4; m++)
#pragma unroll
            for (int n = 0; n < 4; n++) {
                const int col = wn * 64 + n * 16 + lr;
#pragma unroll
                for (int r = 0; r < 4; r++) {
                    const int row = wm * 64 + m * 16 + q4 * 4 + r;
                    float v = acc[m][n][r];
                    if constexpr (BIAS_MODE == 1) v += bias[n0 + col];
                    if constexpr (BIAS_MODE == 2) v += bias[m0 + row];
                    v *= scale;
                    lds[row * 256 + (col ^ (((row >> 2) & 3) << 4))] = f2bf(v);
                }
            }
        __syncthreads();
        // 8 sweeps x 16KB: 16B/lane full-line stores.
#pragma unroll
        for (int i = 0; i < 8; i++) {
            const int g   = i * 1024 + tid;
            const int row = g >> 5;
            const int ch  = g & 31;
            bf16x8 v = *(const bf16x8*)&lds[row * 256 + ((ch * 8) ^ (((row >> 2) & 3) << 4))];
            *(bf16x8*)((unsigned short*)C + (m0 + row) * ldc + n0 + ch * 8) = v;
        }
    } else {
        // f32: two 128-row passes (each 128KB).
        float* fl = (float*)lds;
#pragma unroll
        for (int h = 0; h < 2; h++) {
            __syncthreads();
            if ((wm >> 1) == h) {
#pragma unroll
                for (int m = 0; m < 4; m++)
#pragma unroll
                    for (int n = 0; n < 4; n++) {
                        const int col = wn * 64 + n * 16 + lr;
#pragma unroll
                        for (int r = 0; r < 4; r++) {
                            const int rowh = (wm & 1) * 64 + m * 16 + q4 * 4 + r;  // 0..127
                            float v = acc[m][n][r];
                            if constexpr (BIAS_MODE == 1) v += bias[n0 + col];
                            if constexpr (BIAS_MODE == 2) v += bias[m0 + h * 128 + rowh];
                            v *= scale;
                            fl[rowh * 256 + (col ^ (((rowh >> 2) & 3) << 4))] = v;
                        }
                    }
            }
            __syncthreads();
#pragma unroll
            for (int i = 0; i < 8; i++) {
                const int g   = i * 1024 + tid;
                const int row = g >> 6;          // 64 x 16B chunks per 1KB row
                const int ch  = g & 63;
                float4 v = *(const float4*)&fl[row * 256 + ((ch * 4) ^ (((row >> 2) & 3) << 4))];
                *(float4*)((float*)C + (m0 + h * 128 + row) * ldc + n0 + ch * 4) = v;
            }
        }
    }
}

// Wave-per-row softmax: 1 wave owns a full 1024-elem bf16 row. 16 elems/lane,
// shuffle-only reduction, no barriers, no LDS. Grid = 4096 blocks x 4 waves.
__global__ __launch_bounds__(256) void softmax_wave(unsigned short* __restrict__ base)
{
    const int wave = threadIdx.x >> 6, lane = threadIdx.x & 63;
    unsigned short* p = base + ((long)blockIdx.x * 4 + wave) * 1024;

    bf16x8 v0 = *(const bf16x8*)(p + lane * 8);
    bf16x8 v1 = *(const bf16x8*)(p + 512 + lane * 8);
    float x[16];
#pragma unroll
    for (int i = 0; i < 8; i++) {
        x[i]     = fminf(fmaxf(bf2f((unsigned short)v0[i]), -1e30f), 1e30f);
        x[8 + i] = fminf(fmaxf(bf2f((unsigned short)v1[i]), -1e30f), 1e30f);
    }
    float m = x[0];
#pragma unroll
    for (int i = 1; i < 16; i++) m = fmaxf(m, x[i]);
#pragma unroll
    for (int o = 32; o > 0; o >>= 1) m = fmaxf(m, __shfl_xor(m, o));

    float e[16], s = 0.f;
#pragma unroll
    for (int i = 0; i < 16; i++) { e[i] = __expf(x[i] - m); s += e[i]; }
#pragma unroll
    for (int o = 32; o > 0; o >>= 1) s += __shfl_xor(s, o);
    const float inv = 1.0f / s;

    bf16x8 o0, o1;
#pragma unroll
    for (int i = 0; i < 8; i++) {
        o0[i] = (short)f2bf(e[i] * inv);
        o1[i] = (short)f2bf(e[8 + i] * inv);
    }
    *(bf16x8*)(p + lane * 8) = o0;
    *(bf16x8*)(p + 512 + lane * 8) = o1;
}

extern "C" void kernel_launch(void* const* d_in, const int* in_sizes, int n_in,
                              void* d_out, int out_size, void* d_ws, size_t ws_size,
                              hipStream_t stream) {
    const float* query = (const float*)d_in[0];  // (1024,16,1024) f32, rows l*16+n
    const float* keyp  = (const float*)d_in[1];  // rows s*16+n
    const float* valp  = (const float*)d_in[2];
    const float* wq    = (const float*)d_in[3];  // (1024,1024) f32
    const float* wk    = (const float*)d_in[4];
    const float* wv    = (const float*)d_in[5];
    const float* bias  = (const float*)d_in[6];  // (3072,) f32
    float* out = (float*)d_out;                  // 16M f32 = 64 MB

    unsigned short* WSA = (unsigned short*)d_ws;  // 32 MB
    unsigned short* WSB = WSA + 16777216;         // 32 MB
    unsigned short* OC  = (unsigned short*)d_out; // 32 MB (dead before final PV write)
    unsigned short* OD  = OC + 16777216;          // 32 MB

    const dim3 cblk(256, 1, 1);
    const dim3 gblk(1024, 1, 1);

    // 1) Qproj = (Q @ Wq^T + bq) * E^-0.5 -> OC (bf16, rows l*16+n)  [f32 in]
    gemm_bt2<1, unsigned short, true><<<256, gblk, 0, stream>>>(
        query, wq, OC, bias, 0.03125f, 1024,
        1024, 1024, 1024, 0, 0, 0, 64, 4);
    // 2) Kproj = K @ Wk^T + bk -> OD (bf16, rows s*16+n)  [f32 in]
    gemm_bt2<1, unsigned short, true><<<256, gblk, 0, stream>>>(
        keyp, wk, OD, bias + 1024, 1.0f, 1024,
        1024, 1024, 1024, 0, 0, 0, 64, 4);
    // 3) scores[n][l][s] = Qproj_n @ Kproj_n^T -> WSB  [bf16 in]
    gemm_bt2<0, unsigned short, false><<<256, gblk, 0, stream>>>(
        OC, OD, WSB, nullptr, 1.0f, 1024,
        16384, 16384, 1024, 1024, 1024, 1048576, 4, 4);
    // 4) softmax over s, all 16384 rows, in place (wave-per-row)
    softmax_wave<<<4096, cblk, 0, stream>>>(WSB);
    // 5) Vt[n][f][s] = Wv @ V_n^T + bv[f] (row-bias) -> WSA  [f32 in]
    gemm_bt2<2, unsigned short, true><<<256, gblk, 0, stream>>>(
        wv, valp, WSA, bias + 2048, 1.0f, 1024,
        1024, 16384, 1024, 0, 1024, 1048576, 4, 4);
    // 6) out[(l*16+n)][f] = attn_n[l][:] . Vt_n[f][:] -> d_out (f32)  [bf16 in]
    gemm_bt2<0, float, false><<<256, gblk, 0, stream>>>(
        WSB, WSA, out, nullptr, 1.0f, 1024,
        1024, 1024, 16384, 1048576, 1048576, 1024, 4, 4);
}